// Round 8
// baseline (384.433 us; speedup 1.0000x reference)
//
#include <hip/hip_runtime.h>

#define DDIM 256
#define NEDGE 4096
#define SLEN 64
#define NNODE 1024
#define ROWS 65536

typedef short s16x8 __attribute__((ext_vector_type(8)));
typedef float f32x4 __attribute__((ext_vector_type(4)));

static __device__ __forceinline__ unsigned short f2bf(float f){
  union { float f; unsigned u; } v; v.f = f;
  unsigned r = v.u + 0x7FFFu + ((v.u >> 16) & 1u);
  return (unsigned short)(r >> 16);
}

static __device__ __forceinline__ void gl2lds16(const unsigned short* g, unsigned short* l){
  __builtin_amdgcn_global_load_lds((const __attribute__((address_space(1))) unsigned int*)g,
                                   (__attribute__((address_space(3))) unsigned int*)l, 16, 0, 0);
}

// ---------------- setup: LN (mask-skipped) + weight prep + lengths, fused ----------------
__global__ __launch_bounds__(256) void setup_kernel(const float* nf, const float* lnw, const float* lnb,
                                                    const float* wq, const float* wk, const float* wv, const float* wo,
                                                    const float* bq, const float* bk, const float* bv,
                                                    const float* masks,
                                                    unsigned short* xn, unsigned short* Wqkv, unsigned short* Wo_t,
                                                    float* qkvb, int* lenp){
  int bid = blockIdx.x, tid = threadIdx.x;
  if (bid < 16384){
    int lane = tid & 63;
    int row = bid*4 + (tid >> 6);
    int node = row >> 6;
    unsigned long long bm = __ballot(masks[node*SLEN + lane] > 0.f);
    int len = __popcll(bm);
    int vrows = ((len + 15) >> 4) << 4;
    if ((row & 63) >= vrows) return;     // xn never read for these rows
    const float4 x4 = ((const float4*)(nf + (size_t)row*DDIM))[lane];
    float s  = x4.x + x4.y + x4.z + x4.w;
    float sq = x4.x*x4.x + x4.y*x4.y + x4.z*x4.z + x4.w*x4.w;
    for (int off=1; off<64; off<<=1){ s += __shfl_xor(s, off); sq += __shfl_xor(sq, off); }
    float mu  = s  * (1.0f/DDIM);
    float var = sq * (1.0f/DDIM) - mu*mu;
    float rs  = rsqrtf(var + 1e-5f);
    float4 w4 = ((const float4*)lnw)[lane];
    float4 b4 = ((const float4*)lnb)[lane];
    ushort4 o;
    o.x = f2bf((x4.x - mu)*rs*w4.x + b4.x);
    o.y = f2bf((x4.y - mu)*rs*w4.y + b4.y);
    o.z = f2bf((x4.z - mu)*rs*w4.z + b4.z);
    o.w = f2bf((x4.w - mu)*rs*w4.w + b4.w);
    ((ushort4*)(xn + (size_t)row*DDIM))[lane] = o;
  } else if (bid < 17412){
    int idx = (bid - 16384)*256 + tid;
    if (idx < 196608){
      int mat = idx >> 16;
      int rem = idx & 65535;
      int n = rem >> 8, k = rem & 255;
      const float* W = (mat==0)?wq:(mat==1)?wk:wv;
      Wqkv[(size_t)(mat*256 + n)*256 + k] = f2bf(W[k*256 + n]);
    } else if (idx < 262144){
      int rem = idx - 196608;
      int n = rem >> 8, k = rem & 255;
      Wo_t[(size_t)n*256 + k] = f2bf(wo[k*256 + n]);
    } else if (idx < 262912){
      int i = idx - 262144;
      qkvb[i] = (i < 256) ? bq[i] : (i < 512) ? bk[i-256] : bv[i-512];
    }
  } else {
    int lane = tid & 63;
    int node = (bid - 17412)*4 + (tid >> 6);
    unsigned long long b = __ballot(masks[node*SLEN + lane] > 0.f);
    if (lane == 0) lenp[node] = __popcll(b);
  }
}

// ---------------- CSR: degree + scan + degree-sort + fill, one block ----------------
__global__ void csr_kernel(const int* eidx, int* startp, int* order, int* degp, int* elist){
  __shared__ int deg[NNODE];
  __shared__ int buf[NNODE];
  __shared__ int hist[65];
  __shared__ int cur[NNODE];
  int t = threadIdx.x;
  deg[t] = 0;
  if (t < 65) hist[t] = 0;
  __syncthreads();
  #pragma unroll
  for (int i=0;i<4;i++) atomicAdd(&deg[eidx[i*1024 + t]], 1);
  __syncthreads();
  int d = deg[t];
  buf[t] = d;
  __syncthreads();
  for (int off=1; off<NNODE; off<<=1){
    int v = (t >= off) ? buf[t-off] : 0;
    __syncthreads();
    buf[t] += v;
    __syncthreads();
  }
  int st = buf[t] - d;
  startp[t] = st; degp[t] = d; cur[t] = st;
  int dc = d > 64 ? 64 : d;
  atomicAdd(&hist[dc], 1);
  __syncthreads();
  if (t == 0){
    int acc = 0;
    for (int i=64;i>=0;i--){ int h = hist[i]; hist[i] = acc; acc += h; }
  }
  __syncthreads();
  int pos = atomicAdd(&hist[dc], 1);
  order[pos] = t;
  __syncthreads();
  #pragma unroll
  for (int i=0;i<4;i++){
    int e = i*1024 + t;
    int s = eidx[e];
    int p = atomicAdd(&cur[s], 1);
    elist[p] = eidx[NEDGE + e];
  }
}

// ---------------- QKV GEMM: LDS-free, block=(node, which), wave = 64 rows x 64 cols ----------------
// Q,V written transposed [node][col][token] (packed stores); K token-major [row][col]
__global__ __launch_bounds__(256) void qkv_kernel(const unsigned short* xn, const unsigned short* Wqkv,
                                                  const float* qkvb, const int* lenp,
                                                  unsigned short* qt, unsigned short* kb_, unsigned short* vt){
  int tid = threadIdx.x;
  int lane = tid & 63, wid = tid >> 6, m = lane & 15, quad = lane >> 4;
  int node = blockIdx.x;
  int row0 = node * 64;
  int qtm = (lenp[node] + 15) >> 4;
  int by = blockIdx.y;                 // 0=Q, 1=K, 2=V
  int cb = wid * 64;                   // wave's col base within 256
  f32x4 acc[16];
  #pragma unroll
  for (int i=0;i<16;i++) acc[i] = (f32x4){0.f,0.f,0.f,0.f};
  const unsigned short* ab = xn   + (size_t)(row0 + m)*DDIM + quad*8;
  const unsigned short* bb = Wqkv + ((size_t)by*256 + cb + m)*DDIM + quad*8;
  #pragma unroll
  for (int ks=0; ks<8; ks++){
    s16x8 bf[4];
    #pragma unroll
    for (int nt=0;nt<4;nt++) bf[nt] = *(const s16x8*)(bb + nt*16*DDIM + ks*32);
    #pragma unroll
    for (int mt=0;mt<4;mt++) if (mt < qtm){
      s16x8 af = *(const s16x8*)(ab + mt*16*DDIM + ks*32);
      #pragma unroll
      for (int nt=0;nt<4;nt++)
        acc[mt*4+nt] = __builtin_amdgcn_mfma_f32_16x16x32_bf16(af, bf[nt], acc[mt*4+nt], 0,0,0);
    }
  }
  if (by != 1){
    unsigned short* dst = (by==0) ? qt : vt;
    #pragma unroll
    for (int nt=0;nt<4;nt++){
      int col = cb + nt*16 + m;
      float bbv = qkvb[by*256 + col];
      #pragma unroll
      for (int mt=0;mt<4;mt++) if (mt < qtm){
        ushort4 p;
        p.x = f2bf(acc[mt*4+nt][0] + bbv);
        p.y = f2bf(acc[mt*4+nt][1] + bbv);
        p.z = f2bf(acc[mt*4+nt][2] + bbv);
        p.w = f2bf(acc[mt*4+nt][3] + bbv);
        *(ushort4*)(dst + ((size_t)node*256 + col)*64 + mt*16 + quad*4) = p;
      }
    }
  } else {
    #pragma unroll
    for (int nt=0;nt<4;nt++){
      int col = cb + nt*16 + m;
      float bbv = qkvb[256 + col];
      #pragma unroll
      for (int mt=0;mt<4;mt++) if (mt < qtm)
        #pragma unroll
        for (int r=0;r<4;r++){
          int row = row0 + mt*16 + quad*4 + r;
          kb_[(size_t)row*DDIM + col] = f2bf(acc[mt*4+nt][r] + bbv);
        }
    }
  }
}

// ---------------- attention: block=(src,head), 4 waves=q-tiles, all-async dbuf staging ----------------
__global__ __launch_bounds__(256) void attn_kernel(const unsigned short* qt, const unsigned short* kbuf,
                                                   const unsigned short* vtb, const int* lenp,
                                                   const int* startp, const int* degp, const int* elist,
                                                   const int* order, unsigned short* ctxb){
  __shared__ __align__(16) unsigned short Kt[2][4096];
  __shared__ __align__(16) unsigned short Vt[2][4096];
  __shared__ unsigned short P[4096];
  int tid = threadIdx.x;
  int lane = tid & 63, wid = tid >> 6, m = lane & 15, quad = lane >> 4;
  int src = order[blockIdx.x], h = blockIdx.y;
  int ls = lenp[src];
  int qtm = (ls + 15) >> 4;
  int s0 = startp[src], dg = degp[src];
  bool active = wid < qtm;
  unsigned short* Pw = P + wid*1024;

  s16x8 qf0 = {0,0,0,0,0,0,0,0}, qf1 = {0,0,0,0,0,0,0,0};
  if (active){
    const unsigned short* qtb = qt + ((size_t)src*256 + h*64)*64;  // [d 64][tok 64]
    int tok = wid*16 + m;
    #pragma unroll
    for (int j=0;j<8;j++){
      qf0[j] = (short)qtb[(quad*8 + j)*64 + tok];
      qf1[j] = (short)qtb[(32 + quad*8 + j)*64 + tok];
    }
  }
  f32x4 o[4];
  #pragma unroll
  for (int i=0;i<4;i++) o[i] = (f32x4){0.f,0.f,0.f,0.f};

  int dst0 = 0, dst1 = 0, ld0 = 0;
  if (dg > 0){
    dst0 = elist[s0];
    ld0 = lenp[dst0];
    int kch = ((ld0 + 15) >> 4) * 128;
    #pragma unroll
    for (int i=0;i<2;i++){
      int cid = i*256 + tid;
      if (i*256 + wid*64 < kch){
        int row = cid >> 3, c8 = cid & 7;
        gl2lds16(kbuf + (size_t)(dst0*SLEN + row)*DDIM + h*64 + ((c8 ^ (row&7))<<3), Kt[0] + cid*8);
      }
    }
    const unsigned short* vhead = vtb + ((size_t)dst0*256 + h*64)*64;
    #pragma unroll
    for (int i=0;i<2;i++){
      int cid = i*256 + tid, row = cid >> 3, c8 = cid & 7;
      gl2lds16(vhead + row*64 + ((c8 ^ (row&7))<<3), Vt[0] + cid*8);
    }
  }
  if (dg > 1) dst1 = elist[s0 + 1];
  __syncthreads();

  for (int ei=0; ei<dg; ei++){
    int cur = ei & 1, nxt = cur ^ 1;
    int dst2 = (ei+2 < dg) ? elist[s0 + ei + 2] : 0;
    int ld1 = 0;
    if (ei+1 < dg){
      ld1 = lenp[dst1];
      int kch = ((ld1 + 15) >> 4) * 128;
      #pragma unroll
      for (int i=0;i<2;i++){
        int cid = i*256 + tid;
        if (i*256 + wid*64 < kch){
          int row = cid >> 3, c8 = cid & 7;
          gl2lds16(kbuf + (size_t)(dst1*SLEN + row)*DDIM + h*64 + ((c8 ^ (row&7))<<3), Kt[nxt] + cid*8);
        }
      }
      const unsigned short* vhead = vtb + ((size_t)dst1*256 + h*64)*64;
      #pragma unroll
      for (int i=0;i<2;i++){
        int cid = i*256 + tid, row = cid >> 3, c8 = cid & 7;
        gl2lds16(vhead + row*64 + ((c8 ^ (row&7))<<3), Vt[nxt] + cid*8);
      }
    }
    int ktm = (ld0 + 15) >> 4;
    int ks2 = (ktm + 1) >> 1;
    if (active){
      f32x4 acc[4];
      #pragma unroll
      for (int i=0;i<4;i++) acc[i] = (f32x4){0.f,0.f,0.f,0.f};
      #pragma unroll
      for (int kt=0; kt<4; kt++) if (kt < ktm){
        int key = kt*16 + m;
        s16x8 b0 = *(const s16x8*)(Kt[cur] + key*64 + ((quad ^ (m&7))<<3));
        acc[kt] = __builtin_amdgcn_mfma_f32_16x16x32_bf16(qf0, b0, acc[kt], 0,0,0);
        s16x8 b1 = *(const s16x8*)(Kt[cur] + key*64 + (((4 + quad) ^ (m&7))<<3));
        acc[kt] = __builtin_amdgcn_mfma_f32_16x16x32_bf16(qf1, b1, acc[kt], 0,0,0);
      }
      #pragma unroll
      for (int r=0; r<4; r++){
        float x[4];
        #pragma unroll
        for (int kt=0; kt<4; kt++)
          x[kt] = (kt < ktm && kt*16 + m < ld0) ? __expf(acc[kt][r]*0.125f) : 0.f;
        float s = x[0] + x[1] + x[2] + x[3];
        for (int off=1; off<16; off<<=1) s += __shfl_xor(s, off);
        float inv = 1.0f / s;
        int q = quad*4 + r;
        #pragma unroll
        for (int kt=0; kt<4; kt++) if (kt < 2*ks2){
          int key = kt*16 + m;
          Pw[q*64 + (((key>>3)^(q&7))<<3) + (key&7)] = f2bf(x[kt]*inv);
        }
      }
      #pragma unroll
      for (int ks=0; ks<2; ks++) if (ks < ks2){
        s16x8 pa = *(const s16x8*)(Pw + m*64 + ((((ks*4+quad))^(m&7))<<3));
        #pragma unroll
        for (int dt=0; dt<4; dt++){
          int d = dt*16 + m;
          s16x8 vf = *(const s16x8*)(Vt[cur] + d*64 + (((ks*4+quad)^(d&7))<<3));
          o[dt] = __builtin_amdgcn_mfma_f32_16x16x32_bf16(pa, vf, o[dt], 0,0,0);
        }
      }
    }
    dst0 = dst1; ld0 = ld1; dst1 = dst2;
    __syncthreads();
  }
  if (active){
    #pragma unroll
    for (int dt=0; dt<4; dt++){
      int col = h*64 + dt*16 + m;
      #pragma unroll
      for (int r=0; r<4; r++){
        int row = src*SLEN + wid*16 + quad*4 + r;
        ctxb[(size_t)row*DDIM + col] = f2bf(o[dt][r]);
      }
    }
  }
}

// ---------------- output GEMM: LDS-free, block=node, wave = 64 rows x 64 cols ----------------
__global__ __launch_bounds__(256) void out_kernel(const unsigned short* ctxb, const unsigned short* Wo_t,
                                                  const float* bo, const float* nf, const float* masks,
                                                  const int* lenp, float* out){
  int tid = threadIdx.x;
  int lane = tid & 63, wid = tid >> 6, m = lane & 15, quad = lane >> 4;
  int node = blockIdx.x;
  int row0 = node * 64;
  int qtm = (lenp[node] + 15) >> 4;
  int vrows = qtm << 4;
  int cb = wid * 64;
  f32x4 acc[16];
  #pragma unroll
  for (int i=0;i<16;i++) acc[i] = (f32x4){0.f,0.f,0.f,0.f};
  const unsigned short* ab = ctxb + (size_t)(row0 + m)*DDIM + quad*8;
  const unsigned short* bb = Wo_t + (size_t)(cb + m)*DDIM + quad*8;
  #pragma unroll
  for (int ks=0; ks<8; ks++){
    s16x8 bf[4];
    #pragma unroll
    for (int nt=0;nt<4;nt++) bf[nt] = *(const s16x8*)(bb + nt*16*DDIM + ks*32);
    #pragma unroll
    for (int mt=0;mt<4;mt++) if (mt < qtm){
      s16x8 af = *(const s16x8*)(ab + mt*16*DDIM + ks*32);
      #pragma unroll
      for (int nt=0;nt<4;nt++)
        acc[mt*4+nt] = __builtin_amdgcn_mfma_f32_16x16x32_bf16(af, bf[nt], acc[mt*4+nt], 0,0,0);
    }
  }
  #pragma unroll
  for (int nt=0;nt<4;nt++){
    int col = cb + nt*16 + m;
    float bbv = bo[col];
    #pragma unroll
    for (int mt=0;mt<4;mt++) if (mt < qtm)
      #pragma unroll
      for (int r=0;r<4;r++){
        int row = row0 + mt*16 + quad*4 + r;
        float v = acc[mt*4+nt][r] + bbv + nf[(size_t)row*DDIM + col];
        out[(size_t)row*DDIM + col] = v * masks[row];
      }
  }
  // cooperative zero-fill of fully-masked rows
  for (int r = vrows + wid; r < 64; r += 4)
    ((float4*)(out + (size_t)(row0 + r)*DDIM))[lane] = (float4){0.f,0.f,0.f,0.f};
}

extern "C" void kernel_launch(void* const* d_in, const int* in_sizes, int n_in,
                              void* d_out, int out_size, void* d_ws, size_t ws_size,
                              hipStream_t stream){
  const float* nf    = (const float*)d_in[0];
  const float* masks = (const float*)d_in[1];
  const float* lnw   = (const float*)d_in[2];
  const float* lnb   = (const float*)d_in[3];
  const float* wq    = (const float*)d_in[4];
  const float* bq    = (const float*)d_in[5];
  const float* wk    = (const float*)d_in[6];
  const float* bk    = (const float*)d_in[7];
  const float* wv    = (const float*)d_in[8];
  const float* bv    = (const float*)d_in[9];
  const float* wo    = (const float*)d_in[10];
  const float* bo    = (const float*)d_in[11];
  const int*   eidx  = (const int*)d_in[13];
  float* out = (float*)d_out;

  char* ws = (char*)d_ws;
  const size_t B = (size_t)ROWS * DDIM * 2;
  unsigned short* xn   = (unsigned short*)(ws);
  unsigned short* qt   = (unsigned short*)(ws + B);     // Q transposed [node][col][tok]
  unsigned short* kb   = (unsigned short*)(ws + 2*B);   // K token-major
  unsigned short* vt   = (unsigned short*)(ws + 3*B);   // V transposed [node][col][tok]
  unsigned short* ctxb = (unsigned short*)(ws + 4*B);
  char* wp = ws + 5*B;
  unsigned short* Wqkv = (unsigned short*)(wp);
  unsigned short* Wo_t = (unsigned short*)(wp + 393216);
  float* qkvb         = (float*)(wp + 524288);
  char* ip = wp + 528384;
  int* startp = (int*)(ip);
  int* lenp   = (int*)(ip + 4096);
  int* order  = (int*)(ip + 8192);
  int* degp   = (int*)(ip + 12288);
  int* elist  = (int*)(ip + 16384);

  setup_kernel<<<17668, 256, 0, stream>>>(nf, lnw, lnb, wq, wk, wv, wo, bq, bk, bv,
                                          masks, xn, Wqkv, Wo_t, qkvb, lenp);
  csr_kernel<<<1, 1024, 0, stream>>>(eidx, startp, order, degp, elist);
  qkv_kernel<<<dim3(NNODE, 3), 256, 0, stream>>>(xn, Wqkv, qkvb, lenp, qt, kb, vt);
  attn_kernel<<<dim3(NNODE, 4), 256, 0, stream>>>(qt, kb, vt, lenp, startp, degp, elist, order, ctxb);
  out_kernel<<<NNODE, 256, 0, stream>>>(ctxb, Wo_t, bo, nf, masks, lenp, out);
}

// Round 10
// 361.477 us; speedup vs baseline: 1.0635x; 1.0635x over previous
//
#include <hip/hip_runtime.h>

#define DDIM 256
#define NEDGE 4096
#define SLEN 64
#define NNODE 1024
#define ROWS 65536

typedef short s16x8 __attribute__((ext_vector_type(8)));
typedef float f32x4 __attribute__((ext_vector_type(4)));

static __device__ __forceinline__ unsigned short f2bf(float f){
  union { float f; unsigned u; } v; v.f = f;
  unsigned r = v.u + 0x7FFFu + ((v.u >> 16) & 1u);
  return (unsigned short)(r >> 16);
}

static __device__ __forceinline__ void gl2lds16(const unsigned short* g, unsigned short* l){
  __builtin_amdgcn_global_load_lds((const __attribute__((address_space(1))) unsigned int*)g,
                                   (__attribute__((address_space(3))) unsigned int*)l, 16, 0, 0);
}

// ---------------- setup: LN (mask-skipped) + weight prep + lengths + CSR, fused ----------------
__global__ __launch_bounds__(256) void setup_kernel(const float* nf, const float* lnw, const float* lnb,
                                                    const float* wq, const float* wk, const float* wv, const float* wo,
                                                    const float* bq, const float* bk, const float* bv,
                                                    const float* masks, const int* eidx,
                                                    unsigned short* xn, unsigned short* Wqkv, unsigned short* Wo_t,
                                                    float* qkvb, int* lenp,
                                                    int* startp, int* order, int* degp, int* elist){
  __shared__ int sdeg[NNODE];
  __shared__ int sbuf[256];
  __shared__ int scur[NNODE];
  __shared__ int shist[65];
  int bid = blockIdx.x, tid = threadIdx.x;
  if (bid < 16384){
    int lane = tid & 63;
    int row = bid*4 + (tid >> 6);
    int node = row >> 6;
    unsigned long long bm = __ballot(masks[node*SLEN + lane] > 0.f);
    int len = __popcll(bm);
    int vrows = ((len + 15) >> 4) << 4;
    if ((row & 63) >= vrows) return;     // xn never read for these rows
    const float4 x4 = ((const float4*)(nf + (size_t)row*DDIM))[lane];
    float s  = x4.x + x4.y + x4.z + x4.w;
    float sq = x4.x*x4.x + x4.y*x4.y + x4.z*x4.z + x4.w*x4.w;
    for (int off=1; off<64; off<<=1){ s += __shfl_xor(s, off); sq += __shfl_xor(sq, off); }
    float mu  = s  * (1.0f/DDIM);
    float var = sq * (1.0f/DDIM) - mu*mu;
    float rs  = rsqrtf(var + 1e-5f);
    float4 w4 = ((const float4*)lnw)[lane];
    float4 b4 = ((const float4*)lnb)[lane];
    ushort4 o;
    o.x = f2bf((x4.x - mu)*rs*w4.x + b4.x);
    o.y = f2bf((x4.y - mu)*rs*w4.y + b4.y);
    o.z = f2bf((x4.z - mu)*rs*w4.z + b4.z);
    o.w = f2bf((x4.w - mu)*rs*w4.w + b4.w);
    ((ushort4*)(xn + (size_t)row*DDIM))[lane] = o;
  } else if (bid < 17412){
    int idx = (bid - 16384)*256 + tid;
    if (idx < 196608){
      int mat = idx >> 16;
      int rem = idx & 65535;
      int n = rem >> 8, k = rem & 255;
      const float* W = (mat==0)?wq:(mat==1)?wk:wv;
      Wqkv[(size_t)(mat*256 + n)*256 + k] = f2bf(W[k*256 + n]);
    } else if (idx < 262144){
      int rem = idx - 196608;
      int n = rem >> 8, k = rem & 255;
      Wo_t[(size_t)n*256 + k] = f2bf(wo[k*256 + n]);
    } else if (idx < 262912){
      int i = idx - 262144;
      qkvb[i] = (i < 256) ? bq[i] : (i < 512) ? bk[i-256] : bv[i-512];
    }
  } else if (bid < 17668){
    int lane = tid & 63;
    int node = (bid - 17412)*4 + (tid >> 6);
    unsigned long long b = __ballot(masks[node*SLEN + lane] > 0.f);
    if (lane == 0) lenp[node] = __popcll(b);
  } else {
    // CSR: degree + scan + degree-sort + fill, 256 threads
    int t = tid;
    #pragma unroll
    for (int i=0;i<4;i++) sdeg[i*256 + t] = 0;
    if (t < 65) shist[t] = 0;
    __syncthreads();
    #pragma unroll
    for (int i=0;i<16;i++) atomicAdd(&sdeg[eidx[i*256 + t]], 1);
    __syncthreads();
    int d[4];
    #pragma unroll
    for (int j=0;j<4;j++) d[j] = sdeg[t*4 + j];
    int s = d[0] + d[1] + d[2] + d[3];
    sbuf[t] = s;
    __syncthreads();
    for (int off=1; off<256; off<<=1){
      int v = (t >= off) ? sbuf[t-off] : 0;
      __syncthreads();
      sbuf[t] += v;
      __syncthreads();
    }
    int base = sbuf[t] - s;
    int acc = base;
    #pragma unroll
    for (int j=0;j<4;j++){
      int node = t*4 + j;
      startp[node] = acc; degp[node] = d[j]; scur[node] = acc;
      acc += d[j];
      int dc = d[j] > 64 ? 64 : d[j];
      atomicAdd(&shist[dc], 1);
    }
    __syncthreads();
    if (t == 0){
      int a = 0;
      for (int i=64;i>=0;i--){ int h = shist[i]; shist[i] = a; a += h; }
    }
    __syncthreads();
    #pragma unroll
    for (int j=0;j<4;j++){
      int node = t*4 + j;
      int dc = d[j] > 64 ? 64 : d[j];
      int pos = atomicAdd(&shist[dc], 1);
      order[pos] = node;
    }
    __syncthreads();
    #pragma unroll
    for (int i=0;i<16;i++){
      int e = i*256 + t;
      int sn = eidx[e];
      int p = atomicAdd(&scur[sn], 1);
      elist[p] = eidx[NEDGE + e];
    }
  }
}

// ---------------- QKV GEMM (R7): 64x128 tile, LDS async staging, mask-aware; V transposed ----------------
__global__ __launch_bounds__(256) void qkv_kernel(const unsigned short* xn, const unsigned short* Wqkv,
                                                  const float* qkvb, const int* lenp,
                                                  unsigned short* qb, unsigned short* kb_, unsigned short* vt){
  __shared__ __align__(16) unsigned short As[4096];
  __shared__ __align__(16) unsigned short Bs[8192];
  int tid = threadIdx.x;
  int lane = tid & 63, wid = tid >> 6, m = lane & 15, quad = lane >> 4;
  int row0 = blockIdx.x * 64;
  int node = row0 >> 6;
  int qtm = (lenp[node] + 15) >> 4;
  int vrows = qtm << 4;
  int col0 = blockIdx.y * 128;
  int rw = (wid & 1) * 32, cw = (wid >> 1) * 64;
  int t0 = rw >> 4;
  f32x4 acc[8];
  #pragma unroll
  for (int i=0;i<8;i++) acc[i] = (f32x4){0.f,0.f,0.f,0.f};
  for (int kc = 0; kc < 4; kc++){
    __syncthreads();
    #pragma unroll
    for (int i=0;i<2;i++){
      if (i*32 + wid*8 < vrows){      // wave-uniform predicate
        int cid = i*256 + tid, row = cid >> 3, c8 = cid & 7;
        gl2lds16(xn + (size_t)(row0 + row)*DDIM + kc*64 + ((c8 ^ (row&7))<<3), As + cid*8);
      }
    }
    #pragma unroll
    for (int i=0;i<4;i++){
      int cid = i*256 + tid, row = cid >> 3, c8 = cid & 7;
      gl2lds16(Wqkv + (size_t)(col0 + row)*DDIM + kc*64 + ((c8 ^ (row&7))<<3), Bs + cid*8);
    }
    __syncthreads();
    #pragma unroll
    for (int ks=0; ks<2; ks++){
      int sw = ((ks*4 + quad) ^ (m&7)) << 3;
      s16x8 af[2], bf[4];
      #pragma unroll
      for (int mt=0;mt<2;mt++) if (t0 + mt < qtm) af[mt] = *(const s16x8*)(As + (rw + mt*16 + m)*64 + sw);
      #pragma unroll
      for (int nt=0;nt<4;nt++) bf[nt] = *(const s16x8*)(Bs + (cw + nt*16 + m)*64 + sw);
      #pragma unroll
      for (int mt=0;mt<2;mt++) if (t0 + mt < qtm)
        #pragma unroll
        for (int nt=0;nt<4;nt++)
          acc[mt*4+nt] = __builtin_amdgcn_mfma_f32_16x16x32_bf16(af[mt], bf[nt], acc[mt*4+nt], 0,0,0);
    }
  }
  #pragma unroll
  for (int nt=0;nt<4;nt++){
    int cg = col0 + cw + nt*16 + m;
    int mat = cg >> 8, col = cg & 255;
    float bb = qkvb[cg];
    if (mat < 2){
      unsigned short* ob = (mat==0)?qb:kb_;
      #pragma unroll
      for (int mt=0;mt<2;mt++) if (t0 + mt < qtm)
        #pragma unroll
        for (int r=0;r<4;r++){
          int row = row0 + rw + mt*16 + quad*4 + r;
          ob[(size_t)row*DDIM + col] = f2bf(acc[mt*4+nt][r] + bb);
        }
    } else {
      #pragma unroll
      for (int mt=0;mt<2;mt++) if (t0 + mt < qtm){
        int tok0 = rw + mt*16 + quad*4;
        ushort4 p;
        p.x = f2bf(acc[mt*4+nt][0] + bb);
        p.y = f2bf(acc[mt*4+nt][1] + bb);
        p.z = f2bf(acc[mt*4+nt][2] + bb);
        p.w = f2bf(acc[mt*4+nt][3] + bb);
        *(ushort4*)(vt + ((size_t)node*256 + col)*64 + tok0) = p;
      }
    }
  }
}

// ---------------- attention: block = src node, wave = head; K/V staged once per edge for all heads ----------------
__global__ __launch_bounds__(256) void attn_kernel(const unsigned short* qb, const unsigned short* kbuf,
                                                   const unsigned short* vtb, const int* lenp,
                                                   const int* startp, const int* degp, const int* elist,
                                                   const int* order, unsigned short* ctxb){
  __shared__ __align__(16) unsigned short Kf[16384];  // [tok 64][dim 256], chunk-swizzled per 64-seg
  __shared__ __align__(16) unsigned short Vf[16384];  // [col 256][tok 64], chunk-swizzled
  __shared__ unsigned short P[4096];                  // per wave 1024: [q 16][key 64], swizzled
  int tid = threadIdx.x;
  int lane = tid & 63, h = tid >> 6, m = lane & 15, quad = lane >> 4;
  int src = order[blockIdx.x];
  int ls = lenp[src];
  int qtm = (ls + 15) >> 4;
  int s0 = startp[src], dg = degp[src];
  unsigned short* Pw = P + h*1024;

  // Q fragments for all q-tiles of this head: loaded once, reused over edges
  s16x8 qf[4][2];
  #pragma unroll
  for (int qt_=0; qt_<4; qt_++) if (qt_ < qtm){
    const unsigned short* qbase = qb + (size_t)(src*SLEN + qt_*16 + m)*DDIM + h*64 + quad*8;
    qf[qt_][0] = *(const s16x8*)(qbase);
    qf[qt_][1] = *(const s16x8*)(qbase + 32);
  }
  f32x4 o[16];
  #pragma unroll
  for (int i=0;i<16;i++) o[i] = (f32x4){0.f,0.f,0.f,0.f};

  int dst = 0, ld = 0;
  if (dg > 0){ dst = elist[s0]; ld = lenp[dst]; }

  for (int ei=0; ei<dg; ei++){
    int dstn = (ei+1 < dg) ? elist[s0 + ei + 1] : 0;   // early scalar prefetch
    int ktm = (ld + 15) >> 4;
    int ks2 = (ktm + 1) >> 1;
    int krows = ktm << 4;
    __syncthreads();                 // WAR: prev edge's compute done before re-staging
    // stage K [tok][256]: trim per 16-token tiles (wave-uniform: tok boundary aligned to 16)
    #pragma unroll
    for (int i=0;i<8;i++){
      int cid = i*256 + tid;
      int tok = cid >> 5;
      if (tok < krows){
        int within = cid & 31, seg = within >> 3, c8 = within & 7;
        gl2lds16(kbuf + (size_t)(dst*SLEN + tok)*DDIM + seg*64 + ((c8 ^ (tok&7))<<3), Kf + cid*8);
      }
    }
    // stage V^T [col][tok]: FULL staging — lane-divergent gl2lds is NOT allowed
    // (wave-uniform-base+lane*16 semantics); invalid-token V is finite poison killed by P=0
    #pragma unroll
    for (int i=0;i<8;i++){
      int cid = i*256 + tid;
      int col = cid >> 3, t8 = cid & 7;
      gl2lds16(vtb + ((size_t)dst*256 + col)*64 + ((t8 ^ (col&7))<<3), Vf + cid*8);
    }
    int ldn = (ei+1 < dg) ? lenp[dstn] : 0;
    __syncthreads();                 // staging complete
    // per q-tile: QK^T -> softmax -> P -> PV
    #pragma unroll
    for (int qt_=0; qt_<4; qt_++) if (qt_ < qtm){
      f32x4 acc[4];
      #pragma unroll
      for (int i=0;i<4;i++) acc[i] = (f32x4){0.f,0.f,0.f,0.f};
      #pragma unroll
      for (int kt=0; kt<4; kt++) if (kt < ktm){
        int key = kt*16 + m;
        s16x8 b0 = *(const s16x8*)(Kf + key*DDIM + h*64 + ((quad ^ (key&7))<<3));
        acc[kt] = __builtin_amdgcn_mfma_f32_16x16x32_bf16(qf[qt_][0], b0, acc[kt], 0,0,0);
        s16x8 b1 = *(const s16x8*)(Kf + key*DDIM + h*64 + (((4 + quad) ^ (key&7))<<3));
        acc[kt] = __builtin_amdgcn_mfma_f32_16x16x32_bf16(qf[qt_][1], b1, acc[kt], 0,0,0);
      }
      #pragma unroll
      for (int r=0; r<4; r++){
        float x[4];
        #pragma unroll
        for (int kt=0; kt<4; kt++)
          x[kt] = (kt < ktm && kt*16 + m < ld) ? __expf(acc[kt][r]*0.125f) : 0.f;
        float s = x[0] + x[1] + x[2] + x[3];
        for (int off=1; off<16; off<<=1) s += __shfl_xor(s, off);
        float inv = 1.0f / s;
        int q = quad*4 + r;
        #pragma unroll
        for (int kt=0; kt<4; kt++) if (kt < 2*ks2){
          int key = kt*16 + m;
          Pw[q*64 + (((key>>3)^(q&7))<<3) + (key&7)] = f2bf((kt < ktm) ? x[kt]*inv : 0.f);
        }
      }
      #pragma unroll
      for (int ks=0; ks<2; ks++) if (ks < ks2){
        s16x8 pa = *(const s16x8*)(Pw + m*64 + ((((ks*4+quad))^(m&7))<<3));
        #pragma unroll
        for (int dt=0; dt<4; dt++){
          int col = h*64 + dt*16 + m;
          s16x8 vf = *(const s16x8*)(Vf + col*64 + (((ks*4+quad)^(col&7))<<3));
          o[qt_*4+dt] = __builtin_amdgcn_mfma_f32_16x16x32_bf16(pa, vf, o[qt_*4+dt], 0,0,0);
        }
      }
    }
    dst = dstn; ld = ldn;
  }
  #pragma unroll
  for (int qt_=0; qt_<4; qt_++) if (qt_ < qtm){
    #pragma unroll
    for (int dt=0; dt<4; dt++){
      int col = h*64 + dt*16 + m;
      #pragma unroll
      for (int r=0; r<4; r++){
        int row = src*SLEN + qt_*16 + quad*4 + r;
        ctxb[(size_t)row*DDIM + col] = f2bf(o[qt_*4+dt][r]);
      }
    }
  }
}

// ---------------- output GEMM (R7): mask-aware, valid tiles full path, masked tiles zeros ----------------
__global__ __launch_bounds__(256) void out_kernel(const unsigned short* ctxb, const unsigned short* Wo_t,
                                                  const float* bo, const float* nf, const float* masks,
                                                  const int* lenp, float* out){
  __shared__ __align__(16) unsigned short As[4096];
  __shared__ __align__(16) unsigned short Bs[8192];
  int tid = threadIdx.x;
  int lane = tid & 63, wid = tid >> 6, m = lane & 15, quad = lane >> 4;
  int row0 = blockIdx.x * 64;
  int node = row0 >> 6;
  int qtm = (lenp[node] + 15) >> 4;
  int vrows = qtm << 4;
  int col0 = blockIdx.y * 128;
  int rw = (wid & 1) * 32, cw = (wid >> 1) * 64;
  int t0 = rw >> 4;
  f32x4 acc[8];
  #pragma unroll
  for (int i=0;i<8;i++) acc[i] = (f32x4){0.f,0.f,0.f,0.f};
  for (int kc = 0; kc < 4; kc++){
    __syncthreads();
    #pragma unroll
    for (int i=0;i<2;i++){
      if (i*32 + wid*8 < vrows){
        int cid = i*256 + tid, row = cid >> 3, c8 = cid & 7;
        gl2lds16(ctxb + (size_t)(row0 + row)*DDIM + kc*64 + ((c8 ^ (row&7))<<3), As + cid*8);
      }
    }
    #pragma unroll
    for (int i=0;i<4;i++){
      int cid = i*256 + tid, row = cid >> 3, c8 = cid & 7;
      gl2lds16(Wo_t + (size_t)(col0 + row)*DDIM + kc*64 + ((c8 ^ (row&7))<<3), Bs + cid*8);
    }
    __syncthreads();
    #pragma unroll
    for (int ks=0; ks<2; ks++){
      int sw = ((ks*4 + quad) ^ (m&7)) << 3;
      s16x8 af[2], bf[4];
      #pragma unroll
      for (int mt=0;mt<2;mt++) if (t0 + mt < qtm) af[mt] = *(const s16x8*)(As + (rw + mt*16 + m)*64 + sw);
      #pragma unroll
      for (int nt=0;nt<4;nt++) bf[nt] = *(const s16x8*)(Bs + (cw + nt*16 + m)*64 + sw);
      #pragma unroll
      for (int mt=0;mt<2;mt++) if (t0 + mt < qtm)
        #pragma unroll
        for (int nt=0;nt<4;nt++)
          acc[mt*4+nt] = __builtin_amdgcn_mfma_f32_16x16x32_bf16(af[mt], bf[nt], acc[mt*4+nt], 0,0,0);
    }
  }
  #pragma unroll
  for (int nt=0;nt<4;nt++){
    int col = col0 + cw + nt*16 + m;
    float bb = bo[col];
    #pragma unroll
    for (int mt=0;mt<2;mt++){
      if (t0 + mt < qtm){
        #pragma unroll
        for (int r=0;r<4;r++){
          int row = row0 + rw + mt*16 + quad*4 + r;
          float v = acc[mt*4+nt][r] + bb + nf[(size_t)row*DDIM + col];
          out[(size_t)row*DDIM + col] = v * masks[row];
        }
      } else {
        #pragma unroll
        for (int r=0;r<4;r++){
          int row = row0 + rw + mt*16 + quad*4 + r;
          out[(size_t)row*DDIM + col] = 0.f;
        }
      }
    }
  }
}

extern "C" void kernel_launch(void* const* d_in, const int* in_sizes, int n_in,
                              void* d_out, int out_size, void* d_ws, size_t ws_size,
                              hipStream_t stream){
  const float* nf    = (const float*)d_in[0];
  const float* masks = (const float*)d_in[1];
  const float* lnw   = (const float*)d_in[2];
  const float* lnb   = (const float*)d_in[3];
  const float* wq    = (const float*)d_in[4];
  const float* bq    = (const float*)d_in[5];
  const float* wk    = (const float*)d_in[6];
  const float* bk    = (const float*)d_in[7];
  const float* wv    = (const float*)d_in[8];
  const float* bv    = (const float*)d_in[9];
  const float* wo    = (const float*)d_in[10];
  const float* bo    = (const float*)d_in[11];
  const int*   eidx  = (const int*)d_in[13];
  float* out = (float*)d_out;

  char* ws = (char*)d_ws;
  const size_t B = (size_t)ROWS * DDIM * 2;
  unsigned short* xn   = (unsigned short*)(ws);
  unsigned short* qb   = (unsigned short*)(ws + B);
  unsigned short* kb   = (unsigned short*)(ws + 2*B);   // K token-major
  unsigned short* vt   = (unsigned short*)(ws + 3*B);   // V transposed [node][col][tok]
  unsigned short* ctxb = (unsigned short*)(ws + 4*B);
  char* wp = ws + 5*B;
  unsigned short* Wqkv = (unsigned short*)(wp);
  unsigned short* Wo_t = (unsigned short*)(wp + 393216);
  float* qkvb         = (float*)(wp + 524288);
  char* ip = wp + 528384;
  int* startp = (int*)(ip);
  int* lenp   = (int*)(ip + 4096);
  int* order  = (int*)(ip + 8192);
  int* degp   = (int*)(ip + 12288);
  int* elist  = (int*)(ip + 16384);

  setup_kernel<<<17669, 256, 0, stream>>>(nf, lnw, lnb, wq, wk, wv, wo, bq, bk, bv,
                                          masks, eidx, xn, Wqkv, Wo_t, qkvb, lenp,
                                          startp, order, degp, elist);
  qkv_kernel<<<dim3(NNODE, 6), 256, 0, stream>>>(xn, Wqkv, qkvb, lenp, qb, kb, vt);
  attn_kernel<<<NNODE, 256, 0, stream>>>(qb, kb, vt, lenp, startp, degp, elist, order, ctxb);
  out_kernel<<<dim3(NNODE, 2), 256, 0, stream>>>(ctxb, Wo_t, bo, nf, masks, lenp, out);
}